// Round 18
// baseline (113.594 us; speedup 1.0000x reference)
//
#include <hip/hip_runtime.h>
#include <hip/hip_fp16.h>

// Multi-Scale Deformable Attention forward, fp32 in/out, padded fp16 copy.
//   value:  (B=2, Len=21760, nH=8, D=32) fp32
//   loc:    (B, Q=21760, nH, L=4, P=4, 2) fp32
//   attw:   (B, Q, nH, L, P) fp32
//   out:    (B, Q, nH*D=256) fp32
// Levels: (128,128),(64,64),(32,32),(16,16), starts 0,16384,20480,21504.
//
// R18 = R15 (94 us; best) + ZERO-PADDED levels in the ws fp16 copy.
// R16/R17 proved launch_bounds >(256,4) wrecks regalloc (spill); TLP
// closed. R15 is 54% VALUBusy -> cut VALU: padding removes ALL bounds
// compares/clamps/selects (~40% of point math), and the 4 corners load
// from ONE address + immediate offsets (+64, +Wp*64, +Wp*64+64).
// Padded layout per (b,h) slice: lvl0 130x130 @0, lvl1 66x66 @16900,
// lvl2 34x34 @21256, lvl3 18x18 @22412; 22736 px * 64 B = 1.455 MB/slice,
// 23.28 MB total (memset 0 each call; border stays zero).
// Fallbacks: R15 unpadded fp16 (22.3 MB), then f32.

namespace {
constexpr int kB    = 2;
constexpr int kQ    = 21760;
constexpr int kHd   = 8;
constexpr int kD    = 32;
constexpr int kLen  = 21760;
constexpr int kRow  = kHd * kD;            // 256 elems per spatial position
constexpr int kQBlk = 64;                  // queries per block (4 subs/thread)
constexpr int kBlksPerPair = kQ / kQBlk;   // 340
constexpr int kS3   = 21504;               // level-3 start pixel (unpadded)
constexpr size_t kValElems = (size_t)kB * kLen * kRow;   // 11,141,120

// padded geometry
constexpr int kPadPx    = 22736;           // px per (b,h) slice
constexpr int kSp[4]    = {0, 16900, 21256, 22412};
constexpr size_t kPadBytes = (size_t)kB * kHd * kPadPx * 64;  // 23,281,664
}

__device__ __forceinline__ void fma4(float4& a, float w, const float4 v) {
    a.x = fmaf(w, v.x, a.x);
    a.y = fmaf(w, v.y, a.y);
    a.z = fmaf(w, v.z, a.z);
    a.w = fmaf(w, v.w, a.w);
}

__device__ __forceinline__ void fma8h(float* acc, float w, uint4 u) {
    const __half* hp = (const __half*)&u;
    #pragma unroll
    for (int e = 0; e < 8; ++e)
        acc[e] = fmaf(w, __half2float(hp[e]), acc[e]);   // -> v_fma_mix_f32
}

// ---- Prologue A: fp32 [b][pix][h][ch] -> PADDED fp16 [b][h][ppix][ch] ----
__global__ __launch_bounds__(256) void cvt_pad(
    const float* __restrict__ in, __half* __restrict__ outh)
{
    const int t   = blockIdx.x * 256 + threadIdx.x;   // 0..2,785,279
    const int sub = t & 7;          // 4-float chunk within head row
    const int h   = (t >> 3) & 7;
    const int bp  = t >> 6;         // b*Len + pix
    const int b   = (bp >= kLen) ? 1 : 0;
    const int pix = bp - b * kLen;

    int pidx;
    if (pix < 16384) {
        pidx = ((pix >> 7) + 1) * 130 + (pix & 127) + 1;
    } else if (pix < 20480) {
        const int r = pix - 16384;
        pidx = 16900 + ((r >> 6) + 1) * 66 + (r & 63) + 1;
    } else if (pix < 21504) {
        const int r = pix - 20480;
        pidx = 21256 + ((r >> 5) + 1) * 34 + (r & 31) + 1;
    } else {
        const int r = pix - 21504;
        pidx = 22412 + ((r >> 4) + 1) * 18 + (r & 15) + 1;
    }

    const float4 v = ((const float4*)in)[(size_t)bp * 64 + h * 8 + sub];
    __half2 h0 = __floats2half2_rn(v.x, v.y);
    __half2 h1 = __floats2half2_rn(v.z, v.w);
    uint2 u;
    u.x = *(unsigned*)&h0;
    u.y = *(unsigned*)&h1;
    ((uint2*)outh)[((size_t)(b * kHd + h) * kPadPx + pidx) * 8 + sub] = u;
}

// ---- Main kernel (padded): no bounds logic, 1 addr + imm offsets ----
__global__ __launch_bounds__(256, 4) void msda_fwd_hp(
    const __half* __restrict__ vh,
    const float* __restrict__ loc,
    const float* __restrict__ attw,
    float* __restrict__ out)
{
    const int i    = blockIdx.x;
    const int xcd  = i & 7;
    const int k    = i >> 3;
    const int b    = (k >= kBlksPerPair) ? 1 : 0;
    const int j    = k - b * kBlksPerPair;
    const int h    = xcd;

    const char* slice = (const char*)vh
                      + ((size_t)(b * kHd + h) * kPadPx) * 64;

    // Preload this pair's padded level-3 (324 px * 64 B = 20.25 KB).
    __shared__ __align__(16) char lv3[324 * 64];
    {
        const uint4* src = (const uint4*)(slice + (size_t)kSp[3] * 64);
        uint4* dst = (uint4*)lv3;
        #pragma unroll
        for (int r = 0; r < 6; ++r) {
            const int idx = r * 256 + threadIdx.x;
            if (idx < 324 * 4) dst[idx] = src[idx];
        }
    }
    __syncthreads();

    const int qi   = threadIdx.x >> 2;     // 0..63
    const int sub  = threadIdx.x & 3;      // 8-channel slot
    const int q    = j * kQBlk + qi;
    const int g    = (b * kQ + q) * kHd + h;

    const float4* lp4 = (const float4*)(loc  + (size_t)g * 32);
    const float4* ap4 = (const float4*)(attw + (size_t)g * 16);
    const char* vthr = slice + sub * 16;   // this thread's channel slice

    float acc[8];
    #pragma unroll
    for (int e = 0; e < 8; ++e) acc[e] = 0.f;

    constexpr int   Wd[3] = {128, 64, 32};     // logical dims (fma scale)
    constexpr int   Wp[3] = {130, 66, 34};     // padded strides

    // Levels 0..2: global gather (L2-resident via XCD pinning)
    #pragma unroll
    for (int l = 0; l < 3; ++l) {
        const float Wf = (float)Wd[l];
        const int   Ws = Wp[l];
        const int   Sp = kSp[l];

        const float4 lc0 = lp4[2 * l];
        const float4 lc1 = lp4[2 * l + 1];
        const float4 av  = ap4[l];

        const float lx[4] = {lc0.x, lc0.z, lc1.x, lc1.z};
        const float ly[4] = {lc0.y, lc0.w, lc1.y, lc1.w};
        const float aa[4] = {av.x,  av.y,  av.z,  av.w};

        #pragma unroll
        for (int p = 0; p < 4; ++p) {
            // padded coords: x = lx*W - 0.5 + 1
            const float x = fmaf(lx[p], Wf, 0.5f);
            const float y = fmaf(ly[p], Wf, 0.5f);
            const float x0f = floorf(x);
            const float y0f = floorf(y);
            const float fx = x - x0f;
            const float fy = y - y0f;
            const int   x0 = (int)x0f;
            const int   y0 = (int)y0f;
            const float a  = aa[p];

            const float awy1 = a * fy;
            const float awy0 = a - awy1;
            const float w11  = awy1 * fx;
            const float w10  = awy1 - w11;
            const float w01  = awy0 * fx;
            const float w00  = awy0 - w01;

            const char* pb = vthr + ((Sp + y0 * Ws + x0) << 6);
            const uint4 v00 = *(const uint4*)(pb);
            const uint4 v01 = *(const uint4*)(pb + 64);
            const uint4 v10 = *(const uint4*)(pb + Ws * 64);
            const uint4 v11 = *(const uint4*)(pb + Ws * 64 + 64);

            fma8h(acc, w00, v00);
            fma8h(acc, w01, v01);
            fma8h(acc, w10, v10);
            fma8h(acc, w11, v11);
        }
    }

    // Level 3 from LDS (padded 18x18)
    {
        const float4 lc0 = lp4[6];
        const float4 lc1 = lp4[7];
        const float4 av  = ap4[3];

        const float lx[4] = {lc0.x, lc0.z, lc1.x, lc1.z};
        const float ly[4] = {lc0.y, lc0.w, lc1.y, lc1.w};
        const float aa[4] = {av.x,  av.y,  av.z,  av.w};

        const char* lthr = lv3 + sub * 16;

        #pragma unroll
        for (int p = 0; p < 4; ++p) {
            const float x = fmaf(lx[p], 16.f, 0.5f);
            const float y = fmaf(ly[p], 16.f, 0.5f);
            const float x0f = floorf(x);
            const float y0f = floorf(y);
            const float fx = x - x0f;
            const float fy = y - y0f;
            const int   x0 = (int)x0f;
            const int   y0 = (int)y0f;
            const float a  = aa[p];

            const float awy1 = a * fy;
            const float awy0 = a - awy1;
            const float w11  = awy1 * fx;
            const float w10  = awy1 - w11;
            const float w01  = awy0 * fx;
            const float w00  = awy0 - w01;

            const char* pb = lthr + ((y0 * 18 + x0) << 6);
            const uint4 v00 = *(const uint4*)(pb);
            const uint4 v01 = *(const uint4*)(pb + 64);
            const uint4 v10 = *(const uint4*)(pb + 18 * 64);
            const uint4 v11 = *(const uint4*)(pb + 18 * 64 + 64);

            fma8h(acc, w00, v00);
            fma8h(acc, w01, v01);
            fma8h(acc, w10, v10);
            fma8h(acc, w11, v11);
        }
    }

    float* op = out + ((size_t)(b * kQ + q)) * kRow + h * kD + sub * 8;
    float4 r0, r1;
    r0.x = acc[0]; r0.y = acc[1]; r0.z = acc[2]; r0.w = acc[3];
    r1.x = acc[4]; r1.y = acc[5]; r1.z = acc[6]; r1.w = acc[7];
    ((float4*)op)[0] = r0;
    ((float4*)op)[1] = r1;
}

// ======== R15 fallback pair (unpadded fp16), proven 94 us ========
__global__ __launch_bounds__(256) void cvt_t(
    const float* __restrict__ in, __half* __restrict__ outh)
{
    const int t   = blockIdx.x * 256 + threadIdx.x;
    const int sub = t & 7;
    const int h   = (t >> 3) & 7;
    const int bp  = t >> 6;
    const int b   = (bp >= kLen) ? 1 : 0;
    const int pix = bp - b * kLen;

    const float4 v = ((const float4*)in)[(size_t)bp * 64 + h * 8 + sub];
    __half2 h0 = __floats2half2_rn(v.x, v.y);
    __half2 h1 = __floats2half2_rn(v.z, v.w);
    uint2 u;
    u.x = *(unsigned*)&h0;
    u.y = *(unsigned*)&h1;
    ((uint2*)outh)[((size_t)(b * kHd + h) * kLen + pix) * 8 + sub] = u;
}

__global__ __launch_bounds__(256, 4) void msda_fwd_h(
    const __half* __restrict__ vh,
    const float* __restrict__ loc,
    const float* __restrict__ attw,
    float* __restrict__ out)
{
    const int i    = blockIdx.x;
    const int xcd  = i & 7;
    const int k    = i >> 3;
    const int b    = (k >= kBlksPerPair) ? 1 : 0;
    const int j    = k - b * kBlksPerPair;
    const int h    = xcd;

    const char* slice = (const char*)vh + ((size_t)(b * kHd + h) * kLen) * 64;

    __shared__ __align__(16) char lv3[256 * 64];
    {
        const uint4* src = (const uint4*)(slice + (size_t)kS3 * 64);
        uint4* dst = (uint4*)lv3;
        #pragma unroll
        for (int r = 0; r < 4; ++r)
            dst[r * 256 + threadIdx.x] = src[r * 256 + threadIdx.x];
    }
    __syncthreads();

    const int qi   = threadIdx.x >> 2;
    const int sub  = threadIdx.x & 3;
    const int q    = j * kQBlk + qi;
    const int g    = (b * kQ + q) * kHd + h;

    const float4* lp4 = (const float4*)(loc  + (size_t)g * 32);
    const float4* ap4 = (const float4*)(attw + (size_t)g * 16);
    const char* vthr = slice + sub * 16;

    float acc[8];
    #pragma unroll
    for (int e = 0; e < 8; ++e) acc[e] = 0.f;

    constexpr int Hs[3] = {128, 64, 32};
    constexpr int Ws[3] = {128, 64, 32};
    constexpr int Ss[3] = {0, 16384, 20480};

    #pragma unroll
    for (int l = 0; l < 3; ++l) {
        const int W = Ws[l];
        const int H = Hs[l];
        const int S = Ss[l];

        const float4 lc0 = lp4[2 * l];
        const float4 lc1 = lp4[2 * l + 1];
        const float4 av  = ap4[l];

        const float lx[4] = {lc0.x, lc0.z, lc1.x, lc1.z};
        const float ly[4] = {lc0.y, lc0.w, lc1.y, lc1.w};
        const float aa[4] = {av.x,  av.y,  av.z,  av.w};

        #pragma unroll
        for (int p = 0; p < 4; ++p) {
            const float x = fmaf(lx[p], (float)W, -0.5f);
            const float y = fmaf(ly[p], (float)H, -0.5f);
            const float x0f = floorf(x);
            const float y0f = floorf(y);
            const float fx = x - x0f;
            const float fy = y - y0f;
            const int   x0 = (int)x0f;
            const int   y0 = (int)y0f;
            const float a  = aa[p];

            const bool vx0 = (unsigned)x0       < (unsigned)W;
            const bool vx1 = (unsigned)(x0 + 1) < (unsigned)W;
            const bool vy0 = (unsigned)y0       < (unsigned)H;
            const bool vy1 = (unsigned)(y0 + 1) < (unsigned)H;

            const int xc0 = min(max(x0, 0),     W - 1);
            const int xc1 = min(max(x0 + 1, 0), W - 1);
            const int yc0 = min(max(y0, 0),     H - 1);
            const int yc1 = min(max(y0 + 1, 0), H - 1);

            float w00 = a * (1.f - fx) * (1.f - fy);
            float w01 = a * fx * (1.f - fy);
            float w10 = a * (1.f - fx) * fy;
            float w11 = a * fx * fy;
            w00 = (vy0 && vx0) ? w00 : 0.f;
            w01 = (vy0 && vx1) ? w01 : 0.f;
            w10 = (vy1 && vx0) ? w10 : 0.f;
            w11 = (vy1 && vx1) ? w11 : 0.f;

            const int r0 = (S + yc0 * W) << 6;
            const int r1 = (S + yc1 * W) << 6;
            const uint4 v00 = *(const uint4*)(vthr + r0 + (xc0 << 6));
            const uint4 v01 = *(const uint4*)(vthr + r0 + (xc1 << 6));
            const uint4 v10 = *(const uint4*)(vthr + r1 + (xc0 << 6));
            const uint4 v11 = *(const uint4*)(vthr + r1 + (xc1 << 6));

            fma8h(acc, w00, v00);
            fma8h(acc, w01, v01);
            fma8h(acc, w10, v10);
            fma8h(acc, w11, v11);
        }
    }

    {
        constexpr int W = 16, H = 16;
        const float4 lc0 = lp4[6];
        const float4 lc1 = lp4[7];
        const float4 av  = ap4[3];

        const float lx[4] = {lc0.x, lc0.z, lc1.x, lc1.z};
        const float ly[4] = {lc0.y, lc0.w, lc1.y, lc1.w};
        const float aa[4] = {av.x,  av.y,  av.z,  av.w};

        const char* lthr = lv3 + sub * 16;

        #pragma unroll
        for (int p = 0; p < 4; ++p) {
            const float x = fmaf(lx[p], (float)W, -0.5f);
            const float y = fmaf(ly[p], (float)H, -0.5f);
            const float x0f = floorf(x);
            const float y0f = floorf(y);
            const float fx = x - x0f;
            const float fy = y - y0f;
            const int   x0 = (int)x0f;
            const int   y0 = (int)y0f;
            const float a  = aa[p];

            const bool vx0 = (unsigned)x0       < (unsigned)W;
            const bool vx1 = (unsigned)(x0 + 1) < (unsigned)W;
            const bool vy0 = (unsigned)y0       < (unsigned)H;
            const bool vy1 = (unsigned)(y0 + 1) < (unsigned)H;

            const int xc0 = min(max(x0, 0),     W - 1);
            const int xc1 = min(max(x0 + 1, 0), W - 1);
            const int yc0 = min(max(y0, 0),     H - 1);
            const int yc1 = min(max(y0 + 1, 0), H - 1);

            float w00 = a * (1.f - fx) * (1.f - fy);
            float w01 = a * fx * (1.f - fy);
            float w10 = a * (1.f - fx) * fy;
            float w11 = a * fx * fy;
            w00 = (vy0 && vx0) ? w00 : 0.f;
            w01 = (vy0 && vx1) ? w01 : 0.f;
            w10 = (vy1 && vx0) ? w10 : 0.f;
            w11 = (vy1 && vx1) ? w11 : 0.f;

            const uint4 v00 = *(const uint4*)(lthr + ((yc0 * W + xc0) << 6));
            const uint4 v01 = *(const uint4*)(lthr + ((yc0 * W + xc1) << 6));
            const uint4 v10 = *(const uint4*)(lthr + ((yc1 * W + xc0) << 6));
            const uint4 v11 = *(const uint4*)(lthr + ((yc1 * W + xc1) << 6));

            fma8h(acc, w00, v00);
            fma8h(acc, w01, v01);
            fma8h(acc, w10, v10);
            fma8h(acc, w11, v11);
        }
    }

    float* op = out + ((size_t)(b * kQ + q)) * kRow + h * kD + sub * 8;
    float4 r0, r1;
    r0.x = acc[0]; r0.y = acc[1]; r0.z = acc[2]; r0.w = acc[3];
    r1.x = acc[4]; r1.y = acc[5]; r1.z = acc[6]; r1.w = acc[7];
    ((float4*)op)[0] = r0;
    ((float4*)op)[1] = r1;
}

// ---- Last-resort fp32 kernel (no workspace needed) ----
__global__ __launch_bounds__(256, 4) void msda_fwd_f32(
    const float* __restrict__ value,
    const float* __restrict__ loc,
    const float* __restrict__ attw,
    float* __restrict__ out)
{
    const int i    = blockIdx.x;
    const int xcd  = i & 7;
    const int k    = i >> 3;
    const int bpp  = kQ / 32;
    const int b    = (k >= bpp) ? 1 : 0;
    const int j    = k - b * bpp;
    const int h    = xcd;

    __shared__ float lv3[256 * kD];
    {
        const float* src = value + ((size_t)(b * kLen + kS3)) * kRow + h * kD;
        float4* dst = (float4*)lv3;
        #pragma unroll
        for (int r = 0; r < 8; ++r) {
            const int idx  = r * 256 + threadIdx.x;
            const int pix  = idx >> 3;
            const int quad = idx & 7;
            dst[idx] = *(const float4*)(src + (size_t)pix * kRow + quad * 4);
        }
    }
    __syncthreads();

    const int qi   = threadIdx.x >> 3;
    const int sub  = threadIdx.x & 7;
    const int q    = j * 32 + qi;
    const int g    = (b * kQ + q) * kHd + h;

    const float4* lp4 = (const float4*)(loc  + (size_t)g * 32);
    const float4* ap4 = (const float4*)(attw + (size_t)g * 16);
    const float*  vb  = value + (size_t)b * kLen * kRow + h * kD + sub * 4;

    float4 acc = make_float4(0.f, 0.f, 0.f, 0.f);

    constexpr int Hs[3] = {128, 64, 32};
    constexpr int Ws[3] = {128, 64, 32};
    constexpr int Ss[3] = {0, 16384, 20480};

    #pragma unroll
    for (int l = 0; l < 3; ++l) {
        const int W = Ws[l];
        const int H = Hs[l];
        const int S = Ss[l];

        const float4 lc0 = lp4[2 * l];
        const float4 lc1 = lp4[2 * l + 1];
        const float4 av  = ap4[l];

        const float lx[4] = {lc0.x, lc0.z, lc1.x, lc1.z};
        const float ly[4] = {lc0.y, lc0.w, lc1.y, lc1.w};
        const float aa[4] = {av.x,  av.y,  av.z,  av.w};

        #pragma unroll
        for (int p = 0; p < 4; ++p) {
            const float x = fmaf(lx[p], (float)W, -0.5f);
            const float y = fmaf(ly[p], (float)H, -0.5f);
            const float x0f = floorf(x);
            const float y0f = floorf(y);
            const float fx = x - x0f;
            const float fy = y - y0f;
            const int   x0 = (int)x0f;
            const int   y0 = (int)y0f;
            const float a  = aa[p];

            const bool vx0 = (unsigned)x0       < (unsigned)W;
            const bool vx1 = (unsigned)(x0 + 1) < (unsigned)W;
            const bool vy0 = (unsigned)y0       < (unsigned)H;
            const bool vy1 = (unsigned)(y0 + 1) < (unsigned)H;

            const int xc0 = min(max(x0, 0),     W - 1);
            const int xc1 = min(max(x0 + 1, 0), W - 1);
            const int yc0 = min(max(y0, 0),     H - 1);
            const int yc1 = min(max(y0 + 1, 0), H - 1);

            float w00 = a * (1.f - fx) * (1.f - fy);
            float w01 = a * fx * (1.f - fy);
            float w10 = a * (1.f - fx) * fy;
            float w11 = a * fx * fy;
            w00 = (vy0 && vx0) ? w00 : 0.f;
            w01 = (vy0 && vx1) ? w01 : 0.f;
            w10 = (vy1 && vx0) ? w10 : 0.f;
            w11 = (vy1 && vx1) ? w11 : 0.f;

            const int r0 = (S + yc0 * W) * kRow;
            const int r1 = (S + yc1 * W) * kRow;
            const float4 v00 = *(const float4*)(vb + r0 + xc0 * kRow);
            const float4 v01 = *(const float4*)(vb + r0 + xc1 * kRow);
            const float4 v10 = *(const float4*)(vb + r1 + xc0 * kRow);
            const float4 v11 = *(const float4*)(vb + r1 + xc1 * kRow);

            fma4(acc, w00, v00);
            fma4(acc, w01, v01);
            fma4(acc, w10, v10);
            fma4(acc, w11, v11);
        }
    }

    {
        constexpr int W = 16, H = 16;
        const float4 lc0 = lp4[6];
        const float4 lc1 = lp4[7];
        const float4 av  = ap4[3];

        const float lx[4] = {lc0.x, lc0.z, lc1.x, lc1.z};
        const float ly[4] = {lc0.y, lc0.w, lc1.y, lc1.w};
        const float aa[4] = {av.x,  av.y,  av.z,  av.w};

        #pragma unroll
        for (int p = 0; p < 4; ++p) {
            const float x = fmaf(lx[p], (float)W, -0.5f);
            const float y = fmaf(ly[p], (float)H, -0.5f);
            const float x0f = floorf(x);
            const float y0f = floorf(y);
            const float fx = x - x0f;
            const float fy = y - y0f;
            const int   x0 = (int)x0f;
            const int   y0 = (int)y0f;
            const float a  = aa[p];

            const bool vx0 = (unsigned)x0       < (unsigned)W;
            const bool vx1 = (unsigned)(x0 + 1) < (unsigned)W;
            const bool vy0 = (unsigned)y0       < (unsigned)H;
            const bool vy1 = (unsigned)(y0 + 1) < (unsigned)H;

            const int xc0 = min(max(x0, 0),     W - 1);
            const int xc1 = min(max(x0 + 1, 0), W - 1);
            const int yc0 = min(max(y0, 0),     H - 1);
            const int yc1 = min(max(y0 + 1, 0), H - 1);

            float w00 = a * (1.f - fx) * (1.f - fy);
            float w01 = a * fx * (1.f - fy);
            float w10 = a * (1.f - fx) * fy;
            float w11 = a * fx * fy;
            w00 = (vy0 && vx0) ? w00 : 0.f;
            w01 = (vy0 && vx1) ? w01 : 0.f;
            w10 = (vy1 && vx0) ? w10 : 0.f;
            w11 = (vy1 && vx1) ? w11 : 0.f;

            const float* lbase = lv3 + sub * 4;
            const float4 v00 = *(const float4*)(lbase + (yc0 * W + xc0) * kD);
            const float4 v01 = *(const float4*)(lbase + (yc0 * W + xc1) * kD);
            const float4 v10 = *(const float4*)(lbase + (yc1 * W + xc0) * kD);
            const float4 v11 = *(const float4*)(lbase + (yc1 * W + xc1) * kD);

            fma4(acc, w00, v00);
            fma4(acc, w01, v01);
            fma4(acc, w10, v10);
            fma4(acc, w11, v11);
        }
    }

    *(float4*)(out + ((size_t)(b * kQ + q)) * kRow + h * kD + sub * 4) = acc;
}

extern "C" void kernel_launch(void* const* d_in, const int* in_sizes, int n_in,
                              void* d_out, int out_size, void* d_ws, size_t ws_size,
                              hipStream_t stream) {
    const float* value = (const float*)d_in[0];
    const float* loc   = (const float*)d_in[3];
    const float* attw  = (const float*)d_in[4];
    float* out = (float*)d_out;

    const int nthr = (int)(kValElems / 4);              // 2,785,280
    const int grid = kB * kHd * kBlksPerPair;           // 5440

    if (ws_size >= kPadBytes) {
        __half* vh = (__half*)d_ws;
        hipMemsetAsync(d_ws, 0, kPadBytes, stream);     // zero borders
        cvt_pad<<<nthr / 256, 256, 0, stream>>>(value, vh);
        msda_fwd_hp<<<grid, 256, 0, stream>>>(vh, loc, attw, out);
    } else if (ws_size >= kValElems * sizeof(__half)) {
        __half* vh = (__half*)d_ws;
        cvt_t<<<nthr / 256, 256, 0, stream>>>(value, vh);
        msda_fwd_h<<<grid, 256, 0, stream>>>(vh, loc, attw, out);
    } else {
        const int grid32 = kB * kHd * (kQ / 32);        // 10880
        msda_fwd_f32<<<grid32, 256, 0, stream>>>(value, loc, attw, out);
    }
}

// Round 19
// 83.769 us; speedup vs baseline: 1.3560x; 1.3560x over previous
//
#include <hip/hip_runtime.h>
#include <hip/hip_fp16.h>

// Multi-Scale Deformable Attention forward, fp32 in/out, fp16 transposed copy.
//   value:  (B=2, Len=21760, nH=8, D=32) fp32
//   loc:    (B, Q=21760, nH, L=4, P=4, 2) fp32
//   attw:   (B, Q, nH, L, P) fp32
//   out:    (B, Q, nH*D=256) fp32
// Levels: (128,128),(64,64),(32,32),(16,16), starts 0,16384,20480,21504.
//
// R19 = R15 structure + levels 2 AND 3 staged in LDS (80 KB, contiguous
// pixels 20480..21760 of the transposed slice). Ledger: time tracks
// random-L2 access count (~250 G/s ceiling): fp32 44.6M acc = 175-192us,
// fp16 22.3M acc = 100us; VALU cuts (R18) and occupancy (R16/17) bounce.
// Moving 50% of taps (lvl2+3) to LDS halves L2 pressure.
// 512-thread blocks, kQBlk=128, 2 blocks/CU (LDS-exact), 16 waves/CU.
// XCD pinning kept. No inline asm. Fallbacks: R15 fp16, then f32.

namespace {
constexpr int kB    = 2;
constexpr int kQ    = 21760;
constexpr int kHd   = 8;
constexpr int kD    = 32;
constexpr int kLen  = 21760;
constexpr int kRow  = kHd * kD;            // 256 elems per spatial position
constexpr int kQBlk = 128;                 // queries per 512-thread block
constexpr int kBlksPerPair = kQ / kQBlk;   // 170
constexpr int kS2   = 20480;               // level-2 start pixel
constexpr int kS3   = 21504;               // level-3 start pixel
constexpr size_t kValElems = (size_t)kB * kLen * kRow;   // 11,141,120
}

__device__ __forceinline__ void fma4(float4& a, float w, const float4 v) {
    a.x = fmaf(w, v.x, a.x);
    a.y = fmaf(w, v.y, a.y);
    a.z = fmaf(w, v.z, a.z);
    a.w = fmaf(w, v.w, a.w);
}

__device__ __forceinline__ void fma8h(float* acc, float w, uint4 u) {
    const __half* hp = (const __half*)&u;
    #pragma unroll
    for (int e = 0; e < 8; ++e)
        acc[e] = fmaf(w, __half2float(hp[e]), acc[e]);   // -> v_fma_mix_f32
}

// ---- Prologue: value fp32 [b][pix][h][ch] -> fp16 [b][h][pix][ch] ----
__global__ __launch_bounds__(256) void cvt_t(
    const float* __restrict__ in, __half* __restrict__ outh)
{
    const int t   = blockIdx.x * 256 + threadIdx.x;   // 0..2,785,279
    const int sub = t & 7;
    const int h   = (t >> 3) & 7;
    const int bp  = t >> 6;         // b*Len + pix
    const int b   = (bp >= kLen) ? 1 : 0;
    const int pix = bp - b * kLen;

    const float4 v = ((const float4*)in)[(size_t)bp * 64 + h * 8 + sub];
    __half2 h0 = __floats2half2_rn(v.x, v.y);
    __half2 h1 = __floats2half2_rn(v.z, v.w);
    uint2 u;
    u.x = *(unsigned*)&h0;
    u.y = *(unsigned*)&h1;
    ((uint2*)outh)[((size_t)(b * kHd + h) * kLen + pix) * 8 + sub] = u;
}

// ---- Main kernel: lvl0-1 global, lvl2-3 LDS; 512 threads ----
__global__ __launch_bounds__(512, 4) void msda_fwd_h2(
    const __half* __restrict__ vh,
    const float* __restrict__ loc,
    const float* __restrict__ attw,
    float* __restrict__ out)
{
    const int i    = blockIdx.x;
    const int xcd  = i & 7;
    const int k    = i >> 3;               // 0..339
    const int b    = (k >= kBlksPerPair) ? 1 : 0;
    const int j    = k - b * kBlksPerPair;
    const int h    = xcd;

    const char* slice = (const char*)vh + ((size_t)(b * kHd + h) * kLen) * 64;

    // Stage levels 2+3 (pixels 20480..21760, contiguous 80 KB) into LDS.
    __shared__ __align__(16) char lv23[1280 * 64];
    {
        const uint4* src = (const uint4*)(slice + (size_t)kS2 * 64);
        uint4* dst = (uint4*)lv23;
        #pragma unroll
        for (int r = 0; r < 10; ++r)       // 5120 uint4 / 512 threads
            dst[r * 512 + threadIdx.x] = src[r * 512 + threadIdx.x];
    }
    __syncthreads();

    const int qi   = threadIdx.x >> 2;     // 0..127
    const int sub  = threadIdx.x & 3;      // 8-channel slot
    const int q    = j * kQBlk + qi;
    const int g    = (b * kQ + q) * kHd + h;

    const float4* lp4 = (const float4*)(loc  + (size_t)g * 32);
    const float4* ap4 = (const float4*)(attw + (size_t)g * 16);
    const char* vthr = slice + sub * 16;   // thread's channel slice (global)
    const char* lthr = lv23 + sub * 16;    // thread's channel slice (LDS)

    float acc[8];
    #pragma unroll
    for (int e = 0; e < 8; ++e) acc[e] = 0.f;

    // ---- Levels 0..1: global gather (L2-resident via XCD pinning) ----
    constexpr int WsG[2] = {128, 64};
    constexpr int SsG[2] = {0, 16384};

    #pragma unroll
    for (int l = 0; l < 2; ++l) {
        const int W = WsG[l];
        const int S = SsG[l];

        const float4 lc0 = lp4[2 * l];
        const float4 lc1 = lp4[2 * l + 1];
        const float4 av  = ap4[l];

        const float lx[4] = {lc0.x, lc0.z, lc1.x, lc1.z};
        const float ly[4] = {lc0.y, lc0.w, lc1.y, lc1.w};
        const float aa[4] = {av.x,  av.y,  av.z,  av.w};

        #pragma unroll
        for (int p = 0; p < 4; ++p) {
            // grid_sample(align_corners=False): x = loc_x * W - 0.5
            const float x = fmaf(lx[p], (float)W, -0.5f);
            const float y = fmaf(ly[p], (float)W, -0.5f);
            const float x0f = floorf(x);
            const float y0f = floorf(y);
            const float fx = x - x0f;
            const float fy = y - y0f;
            const int   x0 = (int)x0f;
            const int   y0 = (int)y0f;
            const float a  = aa[p];

            const bool vx0 = (unsigned)x0       < (unsigned)W;
            const bool vx1 = (unsigned)(x0 + 1) < (unsigned)W;
            const bool vy0 = (unsigned)y0       < (unsigned)W;
            const bool vy1 = (unsigned)(y0 + 1) < (unsigned)W;

            const int xc0 = min(max(x0, 0),     W - 1);
            const int xc1 = min(max(x0 + 1, 0), W - 1);
            const int yc0 = min(max(y0, 0),     W - 1);
            const int yc1 = min(max(y0 + 1, 0), W - 1);

            float w00 = a * (1.f - fx) * (1.f - fy);
            float w01 = a * fx * (1.f - fy);
            float w10 = a * (1.f - fx) * fy;
            float w11 = a * fx * fy;
            w00 = (vy0 && vx0) ? w00 : 0.f;
            w01 = (vy0 && vx1) ? w01 : 0.f;
            w10 = (vy1 && vx0) ? w10 : 0.f;
            w11 = (vy1 && vx1) ? w11 : 0.f;

            const int r0 = (S + yc0 * W) << 6;   // bytes (64 B / pixel)
            const int r1 = (S + yc1 * W) << 6;
            const uint4 v00 = *(const uint4*)(vthr + r0 + (xc0 << 6));
            const uint4 v01 = *(const uint4*)(vthr + r0 + (xc1 << 6));
            const uint4 v10 = *(const uint4*)(vthr + r1 + (xc0 << 6));
            const uint4 v11 = *(const uint4*)(vthr + r1 + (xc1 << 6));

            fma8h(acc, w00, v00);
            fma8h(acc, w01, v01);
            fma8h(acc, w10, v10);
            fma8h(acc, w11, v11);
        }
    }

    // ---- Levels 2..3: LDS gather ----
    constexpr int WsL[2] = {32, 16};
    constexpr int BsL[2] = {0, 1024};      // pixel base within lv23

    #pragma unroll
    for (int l = 0; l < 2; ++l) {
        const int W = WsL[l];
        const int Bp = BsL[l];

        const float4 lc0 = lp4[2 * (l + 2)];
        const float4 lc1 = lp4[2 * (l + 2) + 1];
        const float4 av  = ap4[l + 2];

        const float lx[4] = {lc0.x, lc0.z, lc1.x, lc1.z};
        const float ly[4] = {lc0.y, lc0.w, lc1.y, lc1.w};
        const float aa[4] = {av.x,  av.y,  av.z,  av.w};

        #pragma unroll
        for (int p = 0; p < 4; ++p) {
            const float x = fmaf(lx[p], (float)W, -0.5f);
            const float y = fmaf(ly[p], (float)W, -0.5f);
            const float x0f = floorf(x);
            const float y0f = floorf(y);
            const float fx = x - x0f;
            const float fy = y - y0f;
            const int   x0 = (int)x0f;
            const int   y0 = (int)y0f;
            const float a  = aa[p];

            const bool vx0 = (unsigned)x0       < (unsigned)W;
            const bool vx1 = (unsigned)(x0 + 1) < (unsigned)W;
            const bool vy0 = (unsigned)y0       < (unsigned)W;
            const bool vy1 = (unsigned)(y0 + 1) < (unsigned)W;

            const int xc0 = min(max(x0, 0),     W - 1);
            const int xc1 = min(max(x0 + 1, 0), W - 1);
            const int yc0 = min(max(y0, 0),     W - 1);
            const int yc1 = min(max(y0 + 1, 0), W - 1);

            float w00 = a * (1.f - fx) * (1.f - fy);
            float w01 = a * fx * (1.f - fy);
            float w10 = a * (1.f - fx) * fy;
            float w11 = a * fx * fy;
            w00 = (vy0 && vx0) ? w00 : 0.f;
            w01 = (vy0 && vx1) ? w01 : 0.f;
            w10 = (vy1 && vx0) ? w10 : 0.f;
            w11 = (vy1 && vx1) ? w11 : 0.f;

            const int r0 = (Bp + yc0 * W) << 6;
            const int r1 = (Bp + yc1 * W) << 6;
            const uint4 v00 = *(const uint4*)(lthr + r0 + (xc0 << 6));
            const uint4 v01 = *(const uint4*)(lthr + r0 + (xc1 << 6));
            const uint4 v10 = *(const uint4*)(lthr + r1 + (xc0 << 6));
            const uint4 v11 = *(const uint4*)(lthr + r1 + (xc1 << 6));

            fma8h(acc, w00, v00);
            fma8h(acc, w01, v01);
            fma8h(acc, w10, v10);
            fma8h(acc, w11, v11);
        }
    }

    float* op = out + ((size_t)(b * kQ + q)) * kRow + h * kD + sub * 8;
    float4 r0, r1;
    r0.x = acc[0]; r0.y = acc[1]; r0.z = acc[2]; r0.w = acc[3];
    r1.x = acc[4]; r1.y = acc[5]; r1.z = acc[6]; r1.w = acc[7];
    ((float4*)op)[0] = r0;
    ((float4*)op)[1] = r1;
}

// ---- Last-resort fp32 kernel (no workspace needed) ----
__global__ __launch_bounds__(256, 4) void msda_fwd_f32(
    const float* __restrict__ value,
    const float* __restrict__ loc,
    const float* __restrict__ attw,
    float* __restrict__ out)
{
    const int i    = blockIdx.x;
    const int xcd  = i & 7;
    const int k    = i >> 3;
    const int bpp  = kQ / 32;
    const int b    = (k >= bpp) ? 1 : 0;
    const int j    = k - b * bpp;
    const int h    = xcd;

    __shared__ float lv3[256 * kD];
    {
        const float* src = value + ((size_t)(b * kLen + kS3)) * kRow + h * kD;
        float4* dst = (float4*)lv3;
        #pragma unroll
        for (int r = 0; r < 8; ++r) {
            const int idx  = r * 256 + threadIdx.x;
            const int pix  = idx >> 3;
            const int quad = idx & 7;
            dst[idx] = *(const float4*)(src + (size_t)pix * kRow + quad * 4);
        }
    }
    __syncthreads();

    const int qi   = threadIdx.x >> 3;
    const int sub  = threadIdx.x & 7;
    const int q    = j * 32 + qi;
    const int g    = (b * kQ + q) * kHd + h;

    const float4* lp4 = (const float4*)(loc  + (size_t)g * 32);
    const float4* ap4 = (const float4*)(attw + (size_t)g * 16);
    const float*  vb  = value + (size_t)b * kLen * kRow + h * kD + sub * 4;

    float4 acc = make_float4(0.f, 0.f, 0.f, 0.f);

    constexpr int Ws[3] = {128, 64, 32};
    constexpr int Ss[3] = {0, 16384, 20480};

    #pragma unroll
    for (int l = 0; l < 3; ++l) {
        const int W = Ws[l];
        const int S = Ss[l];

        const float4 lc0 = lp4[2 * l];
        const float4 lc1 = lp4[2 * l + 1];
        const float4 av  = ap4[l];

        const float lx[4] = {lc0.x, lc0.z, lc1.x, lc1.z};
        const float ly[4] = {lc0.y, lc0.w, lc1.y, lc1.w};
        const float aa[4] = {av.x,  av.y,  av.z,  av.w};

        #pragma unroll
        for (int p = 0; p < 4; ++p) {
            const float x = fmaf(lx[p], (float)W, -0.5f);
            const float y = fmaf(ly[p], (float)W, -0.5f);
            const float x0f = floorf(x);
            const float y0f = floorf(y);
            const float fx = x - x0f;
            const float fy = y - y0f;
            const int   x0 = (int)x0f;
            const int   y0 = (int)y0f;
            const float a  = aa[p];

            const bool vx0 = (unsigned)x0       < (unsigned)W;
            const bool vx1 = (unsigned)(x0 + 1) < (unsigned)W;
            const bool vy0 = (unsigned)y0       < (unsigned)W;
            const bool vy1 = (unsigned)(y0 + 1) < (unsigned)W;

            const int xc0 = min(max(x0, 0),     W - 1);
            const int xc1 = min(max(x0 + 1, 0), W - 1);
            const int yc0 = min(max(y0, 0),     W - 1);
            const int yc1 = min(max(y0 + 1, 0), W - 1);

            float w00 = a * (1.f - fx) * (1.f - fy);
            float w01 = a * fx * (1.f - fy);
            float w10 = a * (1.f - fx) * fy;
            float w11 = a * fx * fy;
            w00 = (vy0 && vx0) ? w00 : 0.f;
            w01 = (vy0 && vx1) ? w01 : 0.f;
            w10 = (vy1 && vx0) ? w10 : 0.f;
            w11 = (vy1 && vx1) ? w11 : 0.f;

            const int r0 = (S + yc0 * W) * kRow;
            const int r1 = (S + yc1 * W) * kRow;
            const float4 v00 = *(const float4*)(vb + r0 + xc0 * kRow);
            const float4 v01 = *(const float4*)(vb + r0 + xc1 * kRow);
            const float4 v10 = *(const float4*)(vb + r1 + xc0 * kRow);
            const float4 v11 = *(const float4*)(vb + r1 + xc1 * kRow);

            fma4(acc, w00, v00);
            fma4(acc, w01, v01);
            fma4(acc, w10, v10);
            fma4(acc, w11, v11);
        }
    }

    {
        constexpr int W = 16;
        const float4 lc0 = lp4[6];
        const float4 lc1 = lp4[7];
        const float4 av  = ap4[3];

        const float lx[4] = {lc0.x, lc0.z, lc1.x, lc1.z};
        const float ly[4] = {lc0.y, lc0.w, lc1.y, lc1.w};
        const float aa[4] = {av.x,  av.y,  av.z,  av.w};

        #pragma unroll
        for (int p = 0; p < 4; ++p) {
            const float x = fmaf(lx[p], (float)W, -0.5f);
            const float y = fmaf(ly[p], (float)W, -0.5f);
            const float x0f = floorf(x);
            const float y0f = floorf(y);
            const float fx = x - x0f;
            const float fy = y - y0f;
            const int   x0 = (int)x0f;
            const int   y0 = (int)y0f;
            const float a  = aa[p];

            const bool vx0 = (unsigned)x0       < (unsigned)W;
            const bool vx1 = (unsigned)(x0 + 1) < (unsigned)W;
            const bool vy0 = (unsigned)y0       < (unsigned)W;
            const bool vy1 = (unsigned)(y0 + 1) < (unsigned)W;

            const int xc0 = min(max(x0, 0),     W - 1);
            const int xc1 = min(max(x0 + 1, 0), W - 1);
            const int yc0 = min(max(y0, 0),     W - 1);
            const int yc1 = min(max(y0 + 1, 0), W - 1);

            float w00 = a * (1.f - fx) * (1.f - fy);
            float w01 = a * fx * (1.f - fy);
            float w10 = a * (1.f - fx) * fy;
            float w11 = a * fx * fy;
            w00 = (vy0 && vx0) ? w00 : 0.f;
            w01 = (vy0 && vx1) ? w01 : 0.f;
            w10 = (vy1 && vx0) ? w10 : 0.f;
            w11 = (vy1 && vx1) ? w11 : 0.f;

            const float* lbase = lv3 + sub * 4;
            const float4 v00 = *(const float4*)(lbase + (yc0 * W + xc0) * kD);
            const float4 v01 = *(const float4*)(lbase + (yc0 * W + xc1) * kD);
            const float4 v10 = *(const float4*)(lbase + (yc1 * W + xc0) * kD);
            const float4 v11 = *(const float4*)(lbase + (yc1 * W + xc1) * kD);

            fma4(acc, w00, v00);
            fma4(acc, w01, v01);
            fma4(acc, w10, v10);
            fma4(acc, w11, v11);
        }
    }

    *(float4*)(out + ((size_t)(b * kQ + q)) * kRow + h * kD + sub * 4) = acc;
}

extern "C" void kernel_launch(void* const* d_in, const int* in_sizes, int n_in,
                              void* d_out, int out_size, void* d_ws, size_t ws_size,
                              hipStream_t stream) {
    const float* value = (const float*)d_in[0];
    const float* loc   = (const float*)d_in[3];
    const float* attw  = (const float*)d_in[4];
    float* out = (float*)d_out;

    if (ws_size >= kValElems * sizeof(__half)) {
        __half* vh = (__half*)d_ws;
        const int nthr = (int)(kValElems / 4);          // 2,785,280
        cvt_t<<<nthr / 256, 256, 0, stream>>>(value, vh);
        const int grid = kB * kHd * kBlksPerPair;       // 2720
        msda_fwd_h2<<<grid, 512, 0, stream>>>(vh, loc, attw, out);
    } else {
        const int grid32 = kB * kHd * (kQ / 32);        // 10880
        msda_fwd_f32<<<grid32, 256, 0, stream>>>(value, loc, attw, out);
    }
}